// Round 9
// baseline (160.664 us; speedup 1.0000x reference)
//
#include <hip/hip_runtime.h>

#define BB 2
#define SS 2048
#define DD 1024
#define HH 16
#define HDIM 64
#define MTOT 4096  // B*S

typedef unsigned short u16;
typedef __bf16 bf16_t;
typedef bf16_t bf16x8 __attribute__((ext_vector_type(8)));
typedef float floatx4 __attribute__((ext_vector_type(4)));
typedef float floatx16 __attribute__((ext_vector_type(16)));

__device__ __forceinline__ float bf2f(u16 u) {
  union { unsigned int i; float f; } x;
  x.i = ((unsigned int)u) << 16;
  return x.f;
}
// round-to-nearest-even f32 -> bf16 (finite inputs only)
__device__ __forceinline__ u16 f2bf(float f) {
  union { float f; unsigned int i; } x;
  x.f = f;
  unsigned int r = x.i + 0x7fffu + ((x.i >> 16) & 1u);
  return (u16)(r >> 16);
}

// async global->LDS, 16B per lane. LDS dest = wave-uniform base + lane*16.
__device__ __forceinline__ void gload16(const u16* g, u16* l) {
  __builtin_amdgcn_global_load_lds(
      (const __attribute__((address_space(1))) unsigned int*)g,
      (__attribute__((address_space(3))) unsigned int*)l, 16, 0, 0);
}

// ---------------- kernel 1: fp32 -> bf16 cast of hs, Wq, Wk, Wv ----------------
__global__ __launch_bounds__(256) void cast_to_bf16(
    const float* __restrict__ hs, const float* __restrict__ wq,
    const float* __restrict__ wk, const float* __restrict__ wv,
    u16* __restrict__ hs_b, u16* __restrict__ wq_b,
    u16* __restrict__ wk_b, u16* __restrict__ wv_b) {
  int fid = blockIdx.x * 256 + threadIdx.x;  // 0 .. 1835007
  const float* src;
  u16* dst;
  int local;
  if (fid < 1048576) { src = hs; dst = hs_b; local = fid; }
  else if (fid < 1310720) { src = wq; dst = wq_b; local = fid - 1048576; }
  else if (fid < 1572864) { src = wk; dst = wk_b; local = fid - 1310720; }
  else { src = wv; dst = wv_b; local = fid - 1572864; }
  float4 v = reinterpret_cast<const float4*>(src)[local];
  ushort4 o;
  o.x = f2bf(v.x); o.y = f2bf(v.y); o.z = f2bf(v.z); o.w = f2bf(v.w);
  reinterpret_cast<ushort4*>(dst)[local] = o;
}

// ---------------- kernel 2: fused QKV projection, 128x64 tiles / 6 blocks-per-CU ----------------
// C[m,n] = sum_k A[m,k]*W[n,k] + bias[n].  A [4096,1024] bf16, W [1024,1024] bf16 (B^T).
// Round-9: the ONLY untried axis after 7 structural rounds is RESIDENT-BLOCK COUNT.
// All prior variants: 768 blocks of 128x128 = 3 blocks/CU (grid-capped; HW allows 6:
// VGPR 84->6 waves/SIMD, LDS 16K->10, threads->8). This kernel is latency-bound (both
// pipes <25%), so halve the N-tile: 128x64, grid 1536 = 6 resident blocks/CU -> 2x the
// stall interleaving at IDENTICAL per-block structure (r0's proven single-buffer loop,
// gload_lds staging, 32x32x16 MFMA, verified C/D layout). x-major dispatch: 48
// consecutive blocks share one A-panel (was 24) -> FETCH should also drop.
#define BKK 32
__global__ __launch_bounds__(256) void qkv_gemm_kernel(
    const u16* __restrict__ A,
    const u16* __restrict__ Wq, const u16* __restrict__ Wk, const u16* __restrict__ Wv,
    const float* __restrict__ bq, const float* __restrict__ bk, const float* __restrict__ bv,
    u16* __restrict__ Qo, u16* __restrict__ Ko, u16* __restrict__ Vo) {
  __shared__ u16 sA[128 * BKK];  // 8 KiB
  __shared__ u16 sB[64 * BKK];   // 4 KiB  (12 KiB total -> LDS allows 13 blocks/CU)
  const int mt = blockIdx.y, ntall = blockIdx.x;  // y: 0..31, x: 0..47
  const int seg = ntall >> 4, nt = ntall & 15;
  const u16* Wp = (seg == 0) ? Wq : (seg == 1) ? Wk : Wv;
  const float* bp = (seg == 0) ? bq : (seg == 1) ? bk : bv;
  u16* Out = (seg == 0) ? Qo : (seg == 1) ? Ko : Vo;
  const int m0 = mt * 128, n0 = nt * 64;
  const int tid = threadIdx.x;
  const int lane = tid & 63, wave = tid >> 6;
  const int wm = (wave >> 1) * 64, wn = (wave & 1) * 32;
  const int l32 = lane & 31, khalf = lane >> 5;
  // staging: A = 512 cells of 16 B (2/thread), B = 256 cells (1/thread); LDS lane-linear.
  const int grow = tid >> 2;         // 0..63
  const int gcol = (tid & 3) * 8;    // 0..24 (elements)
  floatx16 acc[2] = {};
  for (int k0 = 0; k0 < DD; k0 += BKK) {
    gload16(A + (size_t)(m0 + grow) * DD + k0 + gcol, sA + tid * 8);
    gload16(A + (size_t)(m0 + 64 + grow) * DD + k0 + gcol, sA + (256 + tid) * 8);
    gload16(Wp + (size_t)(n0 + grow) * DD + k0 + gcol, sB + tid * 8);
    __syncthreads();  // drains vmcnt(0) -> LDS tiles complete
#pragma unroll
    for (int kk = 0; kk < 2; ++kk) {
      bf16x8 af[2], bfr;
#pragma unroll
      for (int i = 0; i < 2; ++i)
        af[i] = *reinterpret_cast<const bf16x8*>(sA + (wm + i * 32 + l32) * BKK + kk * 16 + khalf * 8);
      bfr = *reinterpret_cast<const bf16x8*>(sB + (wn + l32) * BKK + kk * 16 + khalf * 8);
#pragma unroll
      for (int i = 0; i < 2; ++i)
        acc[i] = __builtin_amdgcn_mfma_f32_32x32x16_bf16(af[i], bfr, acc[i], 0, 0, 0);
    }
    __syncthreads();
  }
  // epilogue: C/D layout col=lane&31, row=(reg&3)+8*(reg>>2)+4*(lane>>5)
  const int col = n0 + wn + l32;
  const float bias = bp[col];
#pragma unroll
  for (int i = 0; i < 2; ++i) {
#pragma unroll
    for (int reg = 0; reg < 16; ++reg) {
      int row = m0 + wm + i * 32 + (reg & 3) + 8 * (reg >> 2) + 4 * khalf;
      Out[(size_t)row * DD + col] = f2bf(acc[i][reg] + bias);
    }
  }
}

// ---------------- kernel 3: mpart[pc][bh][d][e] = sum_{s in chunk pc} mask[s]*V[s,d]*K[s,e] ----------------
// 8 superchunks of 256 s-rows (4 sub-tiles of 64) x 32 bh = 256 blocks (r0-proven shape).
__global__ __launch_bounds__(256) void m_partial_kernel(
    const u16* __restrict__ Xb, const u16* __restrict__ Yb,
    const float* __restrict__ am, float* __restrict__ mpart) {
  __shared__ float sX[64 * 68];
  __shared__ float sY[64 * 68];
  const int bh = blockIdx.y;     // 0..31
  const int b = bh >> 4, h = bh & 15;
  const int tid = threadIdx.x;
  const int e0 = (tid & 15) * 4, d0 = (tid >> 4) * 4;
  float acc[4][4] = {};
  for (int cs = 0; cs < 4; ++cs) {
    const int s0 = (blockIdx.x * 4 + cs) * 64;
    if (cs) __syncthreads();  // protect LDS before restage
#pragma unroll
    for (int c = 0; c < 2; ++c) {
      int L = tid + c * 256;
      int srow = L >> 3;            // 0..63
      int col = (L & 7) * 8;        // 0..56
      size_t g = (size_t)(b * SS + s0 + srow) * DD + h * HDIM + col;
      uint4 xraw = *reinterpret_cast<const uint4*>(Xb + g);
      uint4 yraw = *reinterpret_cast<const uint4*>(Yb + g);
      float m = (am[b * SS + s0 + srow] >= 0.f) ? 1.f : 0.f;
      unsigned int xw[4] = {xraw.x, xraw.y, xraw.z, xraw.w};
      unsigned int yw[4] = {yraw.x, yraw.y, yraw.z, yraw.w};
#pragma unroll
      for (int q = 0; q < 4; ++q) {
        sX[srow * 68 + col + 2 * q]     = m * bf2f((u16)(xw[q] & 0xffffu));
        sX[srow * 68 + col + 2 * q + 1] = m * bf2f((u16)(xw[q] >> 16));
        sY[srow * 68 + col + 2 * q]     = bf2f((u16)(yw[q] & 0xffffu));
        sY[srow * 68 + col + 2 * q + 1] = bf2f((u16)(yw[q] >> 16));
      }
    }
    __syncthreads();
    for (int s = 0; s < 64; ++s) {
      float4 xx = *reinterpret_cast<const float4*>(&sX[s * 68 + e0]);
      float4 yy = *reinterpret_cast<const float4*>(&sY[s * 68 + d0]);
      float xa[4] = {xx.x, xx.y, xx.z, xx.w};
      float ya[4] = {yy.x, yy.y, yy.z, yy.w};
#pragma unroll
      for (int i = 0; i < 4; ++i)
#pragma unroll
        for (int j = 0; j < 4; ++j) acc[i][j] += xa[i] * ya[j];
    }
  }
  float* outp = mpart + ((size_t)(blockIdx.x * 32 + bh)) * 4096;
#pragma unroll
  for (int i = 0; i < 4; ++i) {
    float4 o = {acc[i][0], acc[i][1], acc[i][2], acc[i][3]};
    *reinterpret_cast<float4*>(&outp[(e0 + i) * 64 + d0]) = o;
  }
}

// ---------------- kernel 4: ctx[m, h*64+d] = sum_e Q[m, h*64+e] * M[e,d]  (MFMA) ----------------
// Inline 8-partial reduction during M staging (mpart 4 MB, L2-resident).
__global__ __launch_bounds__(256) void ctx_kernel(
    const u16* __restrict__ Qb, const float* __restrict__ mpart, float* __restrict__ Out) {
  __shared__ u16 sMT[64 * 72];
  const int m0 = blockIdx.x * 128;
  const int h = blockIdx.y;
  const int b = m0 >> 11;         // 128-row tiles never cross the batch boundary
  const int bh = b * HH + h;
  const int tid = threadIdx.x;
#pragma unroll
  for (int c = 0; c < 4; ++c) {
    int L4 = c * 256 + tid;       // float4 index 0..1023 within the 64x64 M^T block
    float4 s = {0.f, 0.f, 0.f, 0.f};
#pragma unroll
    for (int pc = 0; pc < 8; ++pc) {
      const float4* p4 = reinterpret_cast<const float4*>(mpart + ((size_t)(pc * 32 + bh)) * 4096);
      float4 t = p4[L4];
      s.x += t.x; s.y += t.y; s.z += t.z; s.w += t.w;
    }
    int d = L4 >> 4, e = (L4 & 15) * 4;
    ushort4 o = {f2bf(s.x), f2bf(s.y), f2bf(s.z), f2bf(s.w)};
    *reinterpret_cast<ushort4*>(&sMT[d * 72 + e]) = o;
  }
  __syncthreads();
  const int lane = tid & 63, wave = tid >> 6;
  const int l32 = lane & 31, khalf = lane >> 5;
  const int arow = m0 + wave * 32 + l32;
  const u16* qrow = Qb + (size_t)arow * DD + h * HDIM + khalf * 8;
  bf16x8 af[4], bfr[2][4];
#pragma unroll
  for (int k0 = 0; k0 < 4; ++k0) {
    af[k0] = *reinterpret_cast<const bf16x8*>(qrow + k0 * 16);
#pragma unroll
    for (int j = 0; j < 2; ++j)
      bfr[j][k0] = *reinterpret_cast<const bf16x8*>(
          &sMT[(j * 32 + l32) * 72 + k0 * 16 + khalf * 8]);
  }
  floatx16 acc[2] = {};
#pragma unroll
  for (int j = 0; j < 2; ++j)
#pragma unroll
    for (int k0 = 0; k0 < 4; ++k0)
      acc[j] = __builtin_amdgcn_mfma_f32_32x32x16_bf16(af[k0], bfr[j][k0], acc[j], 0, 0, 0);
  // C/D layout: col = lane&31, row = (reg&3)+8*(reg>>2)+4*khalf
#pragma unroll
  for (int j = 0; j < 2; ++j) {
    int col = h * HDIM + j * 32 + l32;
#pragma unroll
    for (int reg = 0; reg < 16; ++reg) {
      int r = m0 + wave * 32 + (reg & 3) + 8 * (reg >> 2) + 4 * khalf;
      Out[(size_t)r * DD + col] = acc[j][reg];
    }
  }
}

extern "C" void kernel_launch(void* const* d_in, const int* in_sizes, int n_in,
                              void* d_out, int out_size, void* d_ws, size_t ws_size,
                              hipStream_t stream) {
  const float* hs = (const float*)d_in[0];
  const float* am = (const float*)d_in[1];
  const float* wq = (const float*)d_in[2];
  const float* bq = (const float*)d_in[3];
  const float* wk = (const float*)d_in[4];
  const float* bk = (const float*)d_in[5];
  const float* wv = (const float*)d_in[6];
  const float* bv = (const float*)d_in[7];
  float* out = (float*)d_out;
  char* ws = (char*)d_ws;

  // workspace layout (bytes), all 16B-aligned; total ~44 MB
  u16* hs_b = (u16*)(ws);                  // 8 MiB  [4096,1024] bf16
  u16* wq_b = (u16*)(ws + 8388608);        // 2 MiB
  u16* wk_b = (u16*)(ws + 10485760);       // 2 MiB
  u16* wv_b = (u16*)(ws + 12582912);       // 2 MiB
  u16* q_b  = (u16*)(ws + 14680064);       // 8 MiB
  u16* k_b  = (u16*)(ws + 23068672);       // 8 MiB
  u16* v_b  = (u16*)(ws + 31457280);       // 8 MiB
  float* mpart = (float*)(ws + 39845888);  // 4 MiB [8 pc][32 bh][64][64] f32 (M^T partials)

  cast_to_bf16<<<7168, 256, 0, stream>>>(hs, wq, wk, wv, hs_b, wq_b, wk_b, wv_b);
  qkv_gemm_kernel<<<dim3(48, 32), 256, 0, stream>>>(hs_b, wq_b, wk_b, wv_b,
                                                    bq, bk, bv, q_b, k_b, v_b);
  // X=V, Y=K -> partials hold M^T
  m_partial_kernel<<<dim3(8, 32), 256, 0, stream>>>(v_b, k_b, am, mpart);
  ctx_kernel<<<dim3(32, 16), 256, 0, stream>>>(q_b, mpart, out);
}

// Round 10
// 149.987 us; speedup vs baseline: 1.0712x; 1.0712x over previous
//
#include <hip/hip_runtime.h>

#define BB 2
#define SS 2048
#define DD 1024
#define HH 16
#define HDIM 64
#define MTOT 4096  // B*S

typedef unsigned short u16;
typedef __bf16 bf16_t;
typedef bf16_t bf16x8 __attribute__((ext_vector_type(8)));
typedef float floatx4 __attribute__((ext_vector_type(4)));
typedef float floatx16 __attribute__((ext_vector_type(16)));

__device__ __forceinline__ float bf2f(u16 u) {
  union { unsigned int i; float f; } x;
  x.i = ((unsigned int)u) << 16;
  return x.f;
}
// round-to-nearest-even f32 -> bf16 (finite inputs only)
__device__ __forceinline__ u16 f2bf(float f) {
  union { float f; unsigned int i; } x;
  x.f = f;
  unsigned int r = x.i + 0x7fffu + ((x.i >> 16) & 1u);
  return (u16)(r >> 16);
}

// async global->LDS, 16B per lane. LDS dest = wave-uniform base + lane*16.
__device__ __forceinline__ void gload16(const u16* g, u16* l) {
  __builtin_amdgcn_global_load_lds(
      (const __attribute__((address_space(1))) unsigned int*)g,
      (__attribute__((address_space(3))) unsigned int*)l, 16, 0, 0);
}

// ---------------- kernel 1: fp32 -> bf16 cast of hs, Wq, Wk, Wv ----------------
// 44 MB at ~6.3 TB/s -> ~7 us, at the HBM ceiling for this traffic.
__global__ __launch_bounds__(256) void cast_to_bf16(
    const float* __restrict__ hs, const float* __restrict__ wq,
    const float* __restrict__ wk, const float* __restrict__ wv,
    u16* __restrict__ hs_b, u16* __restrict__ wq_b,
    u16* __restrict__ wk_b, u16* __restrict__ wv_b) {
  int fid = blockIdx.x * 256 + threadIdx.x;  // 0 .. 1835007
  const float* src;
  u16* dst;
  int local;
  if (fid < 1048576) { src = hs; dst = hs_b; local = fid; }
  else if (fid < 1310720) { src = wq; dst = wq_b; local = fid - 1048576; }
  else if (fid < 1572864) { src = wk; dst = wk_b; local = fid - 1310720; }
  else { src = wv; dst = wv_b; local = fid - 1572864; }
  float4 v = reinterpret_cast<const float4*>(src)[local];
  ushort4 o;
  o.x = f2bf(v.x); o.y = f2bf(v.y); o.z = f2bf(v.z); o.w = f2bf(v.w);
  reinterpret_cast<ushort4*>(dst)[local] = o;
}

// ---------------- kernel 2: fused QKV projection (FINAL: exact r0 structure) ----------------
// C[m,n] = sum_k A[m,k]*W[n,k] + bias[n].  A [4096,1024] bf16, W [1024,1024] bf16 (B^T).
// Best of 8 measured structural variants (43.0 us). Exhausted axes (all neutral-to-worse):
//   staging mech (gload_lds 43.0 / reg+cvt 60), BK (32: 43.0 / 64: 43.2),
//   bank conflicts (9.4M/4.7M/0 -> no effect, off critical path),
//   prefetch depth (0: 43.0 / 1-deep dbuf: 48.7 / 2-deep 3-buf counted-vmcnt: 46.7),
//   tile (128x128: 43 / 256x256 8-phase: 58.8 / 128x64: 57.5),
//   residency (3 blk/CU: 43 / 6 blk/CU: 57.5), raw-barrier vs __syncthreads, fused cast.
// Model: per-iteration cost scales with STAGED BYTES (r6+r9 closure) -- the staging path
// itself is the floor for this N=1024-class shape; consistent with m102's shape curve.
#define BKK 32
__global__ __launch_bounds__(256) void qkv_gemm_kernel(
    const u16* __restrict__ A,
    const u16* __restrict__ Wq, const u16* __restrict__ Wk, const u16* __restrict__ Wv,
    const float* __restrict__ bq, const float* __restrict__ bk, const float* __restrict__ bv,
    u16* __restrict__ Qo, u16* __restrict__ Ko, u16* __restrict__ Vo) {
  __shared__ u16 sA[128 * BKK];
  __shared__ u16 sB[128 * BKK];
  const int mt = blockIdx.y, ntall = blockIdx.x;
  const int seg = ntall >> 3, nt = ntall & 7;
  const u16* Wp = (seg == 0) ? Wq : (seg == 1) ? Wk : Wv;
  const float* bp = (seg == 0) ? bq : (seg == 1) ? bk : bv;
  u16* Out = (seg == 0) ? Qo : (seg == 1) ? Ko : Vo;
  const int m0 = mt * 128, n0 = nt * 128;
  const int tid = threadIdx.x;
  const int lane = tid & 63, wave = tid >> 6;
  const int wm = (wave >> 1) * 64, wn = (wave & 1) * 64;
  const int l32 = lane & 31, khalf = lane >> 5;   // A/B operand: m=lane&31, k=khalf*8+j
  // staging coords: per wave 2 chunks of 1024B; lane covers 16B, lane-contiguous in LDS.
  const int srow0 = wave * 32 + (lane >> 2);
  const int scol = (lane & 3) * 8;
  floatx16 acc[2][2] = {};
  for (int k0 = 0; k0 < DD; k0 += BKK) {
#pragma unroll
    for (int c = 0; c < 2; ++c) {
      int r = srow0 + c * 16;
      gload16(A + (size_t)(m0 + r) * DD + k0 + scol, sA + r * BKK + scol);
      gload16(Wp + (size_t)(n0 + r) * DD + k0 + scol, sB + r * BKK + scol);
    }
    __syncthreads();  // drains vmcnt(0) -> LDS tiles complete
#pragma unroll
    for (int kk = 0; kk < 2; ++kk) {
      bf16x8 af[2], bfr[2];
#pragma unroll
      for (int i = 0; i < 2; ++i)
        af[i] = *reinterpret_cast<const bf16x8*>(sA + (wm + i * 32 + l32) * BKK + kk * 16 + khalf * 8);
#pragma unroll
      for (int j = 0; j < 2; ++j)
        bfr[j] = *reinterpret_cast<const bf16x8*>(sB + (wn + j * 32 + l32) * BKK + kk * 16 + khalf * 8);
#pragma unroll
      for (int i = 0; i < 2; ++i)
#pragma unroll
        for (int j = 0; j < 2; ++j)
          acc[i][j] = __builtin_amdgcn_mfma_f32_32x32x16_bf16(af[i], bfr[j], acc[i][j], 0, 0, 0);
    }
    __syncthreads();
  }
  // epilogue: C/D layout col=lane&31, row=(reg&3)+8*(reg>>2)+4*(lane>>5)
#pragma unroll
  for (int j = 0; j < 2; ++j) {
    int col = n0 + wn + j * 32 + l32;
    float bias = bp[col];
#pragma unroll
    for (int i = 0; i < 2; ++i) {
#pragma unroll
      for (int reg = 0; reg < 16; ++reg) {
        int row = m0 + wm + i * 32 + (reg & 3) + 8 * (reg >> 2) + 4 * khalf;
        Out[(size_t)row * DD + col] = f2bf(acc[i][j][reg] + bias);
      }
    }
  }
}

// ---------------- kernel 3: mpart[pc][bh][d][e] = sum_{s in chunk pc} mask[s]*V[s,d]*K[s,e] ----------------
// 8 superchunks of 256 s-rows (4 sub-tiles of 64) x 32 bh = 256 blocks (r0-proven shape).
__global__ __launch_bounds__(256) void m_partial_kernel(
    const u16* __restrict__ Xb, const u16* __restrict__ Yb,
    const float* __restrict__ am, float* __restrict__ mpart) {
  __shared__ float sX[64 * 68];
  __shared__ float sY[64 * 68];
  const int bh = blockIdx.y;     // 0..31
  const int b = bh >> 4, h = bh & 15;
  const int tid = threadIdx.x;
  const int e0 = (tid & 15) * 4, d0 = (tid >> 4) * 4;
  float acc[4][4] = {};
  for (int cs = 0; cs < 4; ++cs) {
    const int s0 = (blockIdx.x * 4 + cs) * 64;
    if (cs) __syncthreads();  // protect LDS before restage
#pragma unroll
    for (int c = 0; c < 2; ++c) {
      int L = tid + c * 256;
      int srow = L >> 3;            // 0..63
      int col = (L & 7) * 8;        // 0..56
      size_t g = (size_t)(b * SS + s0 + srow) * DD + h * HDIM + col;
      uint4 xraw = *reinterpret_cast<const uint4*>(Xb + g);
      uint4 yraw = *reinterpret_cast<const uint4*>(Yb + g);
      float m = (am[b * SS + s0 + srow] >= 0.f) ? 1.f : 0.f;
      unsigned int xw[4] = {xraw.x, xraw.y, xraw.z, xraw.w};
      unsigned int yw[4] = {yraw.x, yraw.y, yraw.z, yraw.w};
#pragma unroll
      for (int q = 0; q < 4; ++q) {
        sX[srow * 68 + col + 2 * q]     = m * bf2f((u16)(xw[q] & 0xffffu));
        sX[srow * 68 + col + 2 * q + 1] = m * bf2f((u16)(xw[q] >> 16));
        sY[srow * 68 + col + 2 * q]     = bf2f((u16)(yw[q] & 0xffffu));
        sY[srow * 68 + col + 2 * q + 1] = bf2f((u16)(yw[q] >> 16));
      }
    }
    __syncthreads();
    for (int s = 0; s < 64; ++s) {
      float4 xx = *reinterpret_cast<const float4*>(&sX[s * 68 + e0]);
      float4 yy = *reinterpret_cast<const float4*>(&sY[s * 68 + d0]);
      float xa[4] = {xx.x, xx.y, xx.z, xx.w};
      float ya[4] = {yy.x, yy.y, yy.z, yy.w};
#pragma unroll
      for (int i = 0; i < 4; ++i)
#pragma unroll
        for (int j = 0; j < 4; ++j) acc[i][j] += xa[i] * ya[j];
    }
  }
  float* outp = mpart + ((size_t)(blockIdx.x * 32 + bh)) * 4096;
#pragma unroll
  for (int i = 0; i < 4; ++i) {
    float4 o = {acc[i][0], acc[i][1], acc[i][2], acc[i][3]};
    *reinterpret_cast<float4*>(&outp[(e0 + i) * 64 + d0]) = o;
  }
}

// ---------------- kernel 4: ctx[m, h*64+d] = sum_e Q[m, h*64+e] * M[e,d]  (MFMA) ----------------
// Inline 8-partial reduction during M staging (mpart 4 MB, L2-resident; r6/r7-verified).
__global__ __launch_bounds__(256) void ctx_kernel(
    const u16* __restrict__ Qb, const float* __restrict__ mpart, float* __restrict__ Out) {
  __shared__ u16 sMT[64 * 72];
  const int m0 = blockIdx.x * 128;
  const int h = blockIdx.y;
  const int b = m0 >> 11;         // 128-row tiles never cross the batch boundary
  const int bh = b * HH + h;
  const int tid = threadIdx.x;
#pragma unroll
  for (int c = 0; c < 4; ++c) {
    int L4 = c * 256 + tid;       // float4 index 0..1023 within the 64x64 M^T block
    float4 s = {0.f, 0.f, 0.f, 0.f};
#pragma unroll
    for (int pc = 0; pc < 8; ++pc) {
      const float4* p4 = reinterpret_cast<const float4*>(mpart + ((size_t)(pc * 32 + bh)) * 4096);
      float4 t = p4[L4];
      s.x += t.x; s.y += t.y; s.z += t.z; s.w += t.w;
    }
    int d = L4 >> 4, e = (L4 & 15) * 4;
    ushort4 o = {f2bf(s.x), f2bf(s.y), f2bf(s.z), f2bf(s.w)};
    *reinterpret_cast<ushort4*>(&sMT[d * 72 + e]) = o;
  }
  __syncthreads();
  const int lane = tid & 63, wave = tid >> 6;
  const int l32 = lane & 31, khalf = lane >> 5;
  const int arow = m0 + wave * 32 + l32;
  const u16* qrow = Qb + (size_t)arow * DD + h * HDIM + khalf * 8;
  bf16x8 af[4], bfr[2][4];
#pragma unroll
  for (int k0 = 0; k0 < 4; ++k0) {
    af[k0] = *reinterpret_cast<const bf16x8*>(qrow + k0 * 16);
#pragma unroll
    for (int j = 0; j < 2; ++j)
      bfr[j][k0] = *reinterpret_cast<const bf16x8*>(
          &sMT[(j * 32 + l32) * 72 + k0 * 16 + khalf * 8]);
  }
  floatx16 acc[2] = {};
#pragma unroll
  for (int j = 0; j < 2; ++j)
#pragma unroll
    for (int k0 = 0; k0 < 4; ++k0)
      acc[j] = __builtin_amdgcn_mfma_f32_32x32x16_bf16(af[k0], bfr[j][k0], acc[j], 0, 0, 0);
  // C/D layout: col = lane&31, row = (reg&3)+8*(reg>>2)+4*khalf
#pragma unroll
  for (int j = 0; j < 2; ++j) {
    int col = h * HDIM + j * 32 + l32;
#pragma unroll
    for (int reg = 0; reg < 16; ++reg) {
      int r = m0 + wave * 32 + (reg & 3) + 8 * (reg >> 2) + 4 * khalf;
      Out[(size_t)r * DD + col] = acc[j][reg];
    }
  }
}

extern "C" void kernel_launch(void* const* d_in, const int* in_sizes, int n_in,
                              void* d_out, int out_size, void* d_ws, size_t ws_size,
                              hipStream_t stream) {
  const float* hs = (const float*)d_in[0];
  const float* am = (const float*)d_in[1];
  const float* wq = (const float*)d_in[2];
  const float* bq = (const float*)d_in[3];
  const float* wk = (const float*)d_in[4];
  const float* bk = (const float*)d_in[5];
  const float* wv = (const float*)d_in[6];
  const float* bv = (const float*)d_in[7];
  float* out = (float*)d_out;
  char* ws = (char*)d_ws;

  // workspace layout (bytes), all 16B-aligned; total ~44 MB
  u16* hs_b = (u16*)(ws);                  // 8 MiB  [4096,1024] bf16
  u16* wq_b = (u16*)(ws + 8388608);        // 2 MiB
  u16* wk_b = (u16*)(ws + 10485760);       // 2 MiB
  u16* wv_b = (u16*)(ws + 12582912);       // 2 MiB
  u16* q_b  = (u16*)(ws + 14680064);       // 8 MiB
  u16* k_b  = (u16*)(ws + 23068672);       // 8 MiB
  u16* v_b  = (u16*)(ws + 31457280);       // 8 MiB
  float* mpart = (float*)(ws + 39845888);  // 4 MiB [8 pc][32 bh][64][64] f32 (M^T partials)

  cast_to_bf16<<<7168, 256, 0, stream>>>(hs, wq, wk, wv, hs_b, wq_b, wk_b, wv_b);
  qkv_gemm_kernel<<<dim3(24, 32), 256, 0, stream>>>(hs_b, wq_b, wk_b, wv_b,
                                                    bq, bk, bv, q_b, k_b, v_b);
  // X=V, Y=K -> partials hold M^T
  m_partial_kernel<<<dim3(8, 32), 256, 0, stream>>>(v_b, k_b, am, mpart);
  ctx_kernel<<<dim3(32, 16), 256, 0, stream>>>(q_b, mpart, out);
}